// Round 1
// baseline (1546.780 us; speedup 1.0000x reference)
//
#include <hip/hip_runtime.h>
#include <hip/hip_bf16.h>
#include <math.h>

#define D 256
#define D4 64   // D / 4

typedef __attribute__((ext_vector_type(8))) short bf16x8;
typedef __attribute__((ext_vector_type(4))) float f32x4;

__device__ inline unsigned short f2bf(float f) {
    union { float f; unsigned u; } v; v.f = f;
    unsigned r = v.u + 0x7fffu + ((v.u >> 16) & 1u);   // RNE
    return (unsigned short)(r >> 16);
}

// K_prep: W1,W2 -> bf16; fold BN params into scale/shift
__global__ __launch_bounds__(256) void k_prep(
    const float* __restrict__ W1, const float* __restrict__ W2,
    unsigned short* __restrict__ W1b, unsigned short* __restrict__ W2b,
    const float* g1, const float* be1, const float* m1, const float* v1,
    const float* g2, const float* be2, const float* m2, const float* v2,
    float* s1, float* sh1, float* s2, float* sh2)
{
    int i = blockIdx.x * 256 + threadIdx.x;
    if (i < D * D) {
        W1b[i] = f2bf(W1[i]);
        W2b[i] = f2bf(W2[i]);
    }
    if (i < D) {
        float sc1 = g1[i] * rsqrtf(v1[i] + 1e-5f);
        s1[i] = sc1; sh1[i] = be1[i] - m1[i] * sc1;
        float sc2 = g2[i] * rsqrtf(v2[i] + 1e-5f);
        s2[i] = sc2; sh2[i] = be2[i] - m2[i] * sc2;
    }
}

// K0: h = 2*x  (agg accumulates on top via atomics)
__global__ __launch_bounds__(256) void k_init(
    const float4* __restrict__ x, float4* __restrict__ h, int n4)
{
    int i = blockIdx.x * 256 + threadIdx.x;
    if (i < n4) {
        float4 v = x[i];
        h[i] = make_float4(2.f * v.x, 2.f * v.y, 2.f * v.z, 2.f * v.w);
    }
}

// K1: h[dst] += relu(x[src] + edge_attr)   one thread per (edge, float4-chunk)
__global__ __launch_bounds__(256) void k_scatter(
    const float4* __restrict__ x, const float4* __restrict__ ea,
    const int* __restrict__ ei, float* __restrict__ h, int E_)
{
    int i = blockIdx.x * 256 + threadIdx.x;
    if (i >= E_ * D4) return;
    int e = i >> 6;
    int c = i & 63;
    int src = ei[e];
    int dst = ei[E_ + e];
    float4 xv = x[(long)src * D4 + c];
    float4 av = ea[(long)i];
    float mx = fmaxf(xv.x + av.x, 0.f);
    float my = fmaxf(xv.y + av.y, 0.f);
    float mz = fmaxf(xv.z + av.z, 0.f);
    float mw = fmaxf(xv.w + av.w, 0.f);
    float* p = h + (long)dst * D + c * 4;
    atomicAdd(p + 0, mx);
    atomicAdd(p + 1, my);
    atomicAdd(p + 2, mz);
    atomicAdd(p + 3, mw);
}

// K2: a_bf = bf16(BN1(h))
__global__ __launch_bounds__(256) void k_bn1(
    const float4* __restrict__ h, ushort4* __restrict__ a,
    const float* __restrict__ s1, const float* __restrict__ sh1, int n4)
{
    int i = blockIdx.x * 256 + threadIdx.x;
    if (i >= n4) return;
    int c = (i & 63) * 4;
    float4 v = h[i];
    ushort4 o;
    o.x = f2bf(v.x * s1[c + 0] + sh1[c + 0]);
    o.y = f2bf(v.y * s1[c + 1] + sh1[c + 1]);
    o.z = f2bf(v.z * s1[c + 2] + sh1[c + 2]);
    o.w = f2bf(v.w * s1[c + 3] + sh1[c + 3]);
    a[i] = o;
}

// GEMM1: G = bf16(gelu_exact(A @ W1^T + b1));   A,[M,256] bf16; W1b [256,256] bf16 (row = out col)
__global__ __launch_bounds__(256) void k_gemm1(
    const unsigned short* __restrict__ A, const unsigned short* __restrict__ W,
    const float* __restrict__ bias, unsigned short* __restrict__ G, int M)
{
    int wave = threadIdx.x >> 6;
    int lane = threadIdx.x & 63;
    int gw = blockIdx.x * 4 + wave;
    int m_base = gw * 16;
    if (m_base >= M) return;
    int l16 = lane & 15, quad = lane >> 4;

    const bf16x8* Arow = (const bf16x8*)(A + ((long)(m_base + l16) * D + quad * 8));
    bf16x8 afrag[8];
#pragma unroll
    for (int s = 0; s < 8; ++s) afrag[s] = Arow[s * 4];   // stride 32 bf16 per K-step

#pragma unroll
    for (int nt = 0; nt < 16; ++nt) {
        int ncol = nt * 16 + l16;
        const bf16x8* Wrow = (const bf16x8*)(W + ((long)ncol * D + quad * 8));
        f32x4 acc0 = {0.f, 0.f, 0.f, 0.f};
        f32x4 acc1 = {0.f, 0.f, 0.f, 0.f};
#pragma unroll
        for (int s = 0; s < 8; s += 2) {
            acc0 = __builtin_amdgcn_mfma_f32_16x16x32_bf16(afrag[s],     Wrow[s * 4],       acc0, 0, 0, 0);
            acc1 = __builtin_amdgcn_mfma_f32_16x16x32_bf16(afrag[s + 1], Wrow[(s + 1) * 4], acc1, 0, 0, 0);
        }
        float b = bias[ncol];
#pragma unroll
        for (int r = 0; r < 4; ++r) {
            int row = m_base + quad * 4 + r;
            float t = acc0[r] + acc1[r] + b;
            float g = 0.5f * t * (1.f + erff(t * 0.70710678118654752f));
            G[(long)row * D + ncol] = f2bf(g);
        }
    }
}

// GEMM2: out = BN2(h + G @ W2^T + b2)
__global__ __launch_bounds__(256) void k_gemm2(
    const unsigned short* __restrict__ A, const unsigned short* __restrict__ W,
    const float* __restrict__ bias, const float* __restrict__ h,
    const float* __restrict__ s2, const float* __restrict__ sh2,
    float* __restrict__ out, int M)
{
    int wave = threadIdx.x >> 6;
    int lane = threadIdx.x & 63;
    int gw = blockIdx.x * 4 + wave;
    int m_base = gw * 16;
    if (m_base >= M) return;
    int l16 = lane & 15, quad = lane >> 4;

    const bf16x8* Arow = (const bf16x8*)(A + ((long)(m_base + l16) * D + quad * 8));
    bf16x8 afrag[8];
#pragma unroll
    for (int s = 0; s < 8; ++s) afrag[s] = Arow[s * 4];

#pragma unroll
    for (int nt = 0; nt < 16; ++nt) {
        int ncol = nt * 16 + l16;
        const bf16x8* Wrow = (const bf16x8*)(W + ((long)ncol * D + quad * 8));
        f32x4 acc0 = {0.f, 0.f, 0.f, 0.f};
        f32x4 acc1 = {0.f, 0.f, 0.f, 0.f};
#pragma unroll
        for (int s = 0; s < 8; s += 2) {
            acc0 = __builtin_amdgcn_mfma_f32_16x16x32_bf16(afrag[s],     Wrow[s * 4],       acc0, 0, 0, 0);
            acc1 = __builtin_amdgcn_mfma_f32_16x16x32_bf16(afrag[s + 1], Wrow[(s + 1) * 4], acc1, 0, 0, 0);
        }
        float b = bias[ncol];
        float sc = s2[ncol], sh = sh2[ncol];
#pragma unroll
        for (int r = 0; r < 4; ++r) {
            int row = m_base + quad * 4 + r;
            float f = acc0[r] + acc1[r] + b;
            float t = h[(long)row * D + ncol] + f;
            out[(long)row * D + ncol] = t * sc + sh;
        }
    }
}

extern "C" void kernel_launch(void* const* d_in, const int* in_sizes, int n_in,
                              void* d_out, int out_size, void* d_ws, size_t ws_size,
                              hipStream_t stream) {
    const float* x   = (const float*)d_in[0];
    const int*   ei  = (const int*)d_in[1];
    const float* ea  = (const float*)d_in[2];
    const float* W1  = (const float*)d_in[3];
    const float* b1  = (const float*)d_in[4];
    const float* W2  = (const float*)d_in[5];
    const float* b2  = (const float*)d_in[6];
    const float* g1  = (const float*)d_in[7];
    const float* be1 = (const float*)d_in[8];
    const float* m1  = (const float*)d_in[9];
    const float* v1  = (const float*)d_in[10];
    const float* g2  = (const float*)d_in[11];
    const float* be2 = (const float*)d_in[12];
    const float* m2  = (const float*)d_in[13];
    const float* v2  = (const float*)d_in[14];
    float* out = (float*)d_out;

    int N_ = in_sizes[0] / D;
    int E_ = in_sizes[2] / D;

    char* ws = (char*)d_ws;
    size_t off = 0;
    float* h = (float*)(ws + off);            off += (size_t)N_ * D * 4;
    unsigned short* abf = (unsigned short*)(ws + off); off += (size_t)N_ * D * 2;
    unsigned short* gbf = (unsigned short*)(ws + off); off += (size_t)N_ * D * 2;
    unsigned short* W1b = (unsigned short*)(ws + off); off += (size_t)D * D * 2;
    unsigned short* W2b = (unsigned short*)(ws + off); off += (size_t)D * D * 2;
    float* s1  = (float*)(ws + off); off += D * 4;
    float* sh1 = (float*)(ws + off); off += D * 4;
    float* s2  = (float*)(ws + off); off += D * 4;
    float* sh2 = (float*)(ws + off); off += D * 4;

    int n4 = N_ * D4;

    k_prep<<<(D * D + 255) / 256, 256, 0, stream>>>(W1, W2, W1b, W2b,
        g1, be1, m1, v1, g2, be2, m2, v2, s1, sh1, s2, sh2);
    k_init<<<(n4 + 255) / 256, 256, 0, stream>>>((const float4*)x, (float4*)h, n4);
    int tot = E_ * D4;
    k_scatter<<<(tot + 255) / 256, 256, 0, stream>>>((const float4*)x, (const float4*)ea, ei, h, E_);
    k_bn1<<<(n4 + 255) / 256, 256, 0, stream>>>((const float4*)h, (ushort4*)abf, s1, sh1, n4);

    int nwaves = (N_ + 15) / 16;
    int gblocks = (nwaves + 3) / 4;
    k_gemm1<<<gblocks, 256, 0, stream>>>(abf, W1b, b1, gbf, N_);
    k_gemm2<<<gblocks, 256, 0, stream>>>(gbf, W2b, b2, h, s2, sh2, out, N_);
}

// Round 2
// 695.521 us; speedup vs baseline: 2.2239x; 2.2239x over previous
//
#include <hip/hip_runtime.h>
#include <hip/hip_bf16.h>
#include <math.h>

#define D 256
#define D4 64   // D / 4

typedef __attribute__((ext_vector_type(8))) short bf16x8;
typedef __attribute__((ext_vector_type(4))) float f32x4;

__device__ inline unsigned short f2bf(float f) {
    union { float f; unsigned u; } v; v.f = f;
    unsigned r = v.u + 0x7fffu + ((v.u >> 16) & 1u);   // RNE
    return (unsigned short)(r >> 16);
}

// W1,W2 -> bf16; fold BN params into scale/shift
__global__ __launch_bounds__(256) void k_prep(
    const float* __restrict__ W1, const float* __restrict__ W2,
    unsigned short* __restrict__ W1b, unsigned short* __restrict__ W2b,
    const float* g1, const float* be1, const float* m1, const float* v1,
    const float* g2, const float* be2, const float* m2, const float* v2,
    float* s1, float* sh1, float* s2, float* sh2)
{
    int i = blockIdx.x * 256 + threadIdx.x;
    if (i < D * D) {
        W1b[i] = f2bf(W1[i]);
        W2b[i] = f2bf(W2[i]);
    }
    if (i < D) {
        float sc1 = g1[i] * rsqrtf(v1[i] + 1e-5f);
        s1[i] = sc1; sh1[i] = be1[i] - m1[i] * sc1;
        float sc2 = g2[i] * rsqrtf(v2[i] + 1e-5f);
        s2[i] = sc2; sh2[i] = be2[i] - m2[i] * sc2;
    }
}

// ---- counting sort of edges by dst ----
__global__ __launch_bounds__(256) void k_zero(int* counts, int* cursor, int n) {
    int i = blockIdx.x * 256 + threadIdx.x;
    if (i < n) { counts[i] = 0; cursor[i] = 0; }
}

__global__ __launch_bounds__(256) void k_hist(const int* __restrict__ ei, int* counts, int E_) {
    int e = blockIdx.x * 256 + threadIdx.x;
    if (e < E_) atomicAdd(&counts[ei[E_ + e]], 1);
}

__global__ __launch_bounds__(256) void k_scan1(const int* __restrict__ counts,
                                               int* offs, int* partials, int n) {
    __shared__ int tmp[256];
    int tid = threadIdx.x, i = blockIdx.x * 256 + tid;
    int v = (i < n) ? counts[i] : 0;
    tmp[tid] = v; __syncthreads();
    for (int d = 1; d < 256; d <<= 1) {
        int t = (tid >= d) ? tmp[tid - d] : 0;
        __syncthreads();
        tmp[tid] += t;
        __syncthreads();
    }
    if (i < n) offs[i] = tmp[tid] - v;          // exclusive
    if (tid == 255) partials[blockIdx.x] = tmp[255];
}

__global__ __launch_bounds__(256) void k_scan2(int* partials, int nb) {
    __shared__ int tmp[256];
    int tid = threadIdx.x;
    int v = (tid < nb) ? partials[tid] : 0;
    tmp[tid] = v; __syncthreads();
    for (int d = 1; d < 256; d <<= 1) {
        int t = (tid >= d) ? tmp[tid - d] : 0;
        __syncthreads();
        tmp[tid] += t;
        __syncthreads();
    }
    if (tid < nb) partials[tid] = tmp[tid] - v; // exclusive
}

__global__ __launch_bounds__(256) void k_scan3(int* offs, const int* __restrict__ partials,
                                               int n, int E_) {
    int i = blockIdx.x * 256 + threadIdx.x;
    if (i < n) offs[i] += partials[blockIdx.x];
    if (i == 0) offs[n] = E_;
}

__global__ __launch_bounds__(256) void k_bucket(const int* __restrict__ ei,
                                                const int* __restrict__ offs,
                                                int* cursor, int* sorted, int E_) {
    int e = blockIdx.x * 256 + threadIdx.x;
    if (e < E_) {
        int d = ei[E_ + e];
        int pos = offs[d] + atomicAdd(&cursor[d], 1);
        sorted[pos] = e;
    }
}

// ---- aggregation: one wave per dst row, no atomics; fuses h=2x+agg and BN1->bf16 ----
__global__ __launch_bounds__(256) void k_agg(
    const float4* __restrict__ x, const float4* __restrict__ ea,
    const int* __restrict__ ei, const int* __restrict__ offs,
    const int* __restrict__ sorted,
    const float* __restrict__ s1, const float* __restrict__ sh1,
    float4* __restrict__ h, ushort4* __restrict__ abf, int N_, int E_)
{
    int wave = threadIdx.x >> 6, lane = threadIdx.x & 63;
    int row = blockIdx.x * 4 + wave;
    if (row >= N_) return;
    float4 xv = x[(long)row * D4 + lane];
    float ax = 2.f * xv.x, ay = 2.f * xv.y, az = 2.f * xv.z, aw = 2.f * xv.w;
    int b = offs[row], en = offs[row + 1];
    for (int i = b; i < en; ++i) {
        int e = sorted[i];
        int s = ei[e];
        float4 sv = x[(long)s * D4 + lane];
        float4 av = ea[(long)e * D4 + lane];
        ax += fmaxf(sv.x + av.x, 0.f);
        ay += fmaxf(sv.y + av.y, 0.f);
        az += fmaxf(sv.z + av.z, 0.f);
        aw += fmaxf(sv.w + av.w, 0.f);
    }
    h[(long)row * D4 + lane] = make_float4(ax, ay, az, aw);
    float4 sc = ((const float4*)s1)[lane];
    float4 sh = ((const float4*)sh1)[lane];
    ushort4 o;
    o.x = f2bf(ax * sc.x + sh.x);
    o.y = f2bf(ay * sc.y + sh.y);
    o.z = f2bf(az * sc.z + sh.z);
    o.w = f2bf(aw * sc.w + sh.w);
    abf[(long)row * D4 + lane] = o;
}

__device__ inline float gelu_tanh(float t) {
    // tanh-form GELU; tanh via hw exp. |err| vs exact-erf GELU < ~3e-3.
    float z = 0.7978845608028654f * (t + 0.044715f * t * t * t);
    float e = __expf(2.f * z);
    return 0.5f * t * (2.f - 2.f / (e + 1.f));
}

// GEMM1: G = bf16(gelu(A @ W1^T + b1))
__global__ __launch_bounds__(256) void k_gemm1(
    const unsigned short* __restrict__ A, const unsigned short* __restrict__ W,
    const float* __restrict__ bias, unsigned short* __restrict__ G, int M)
{
    int wave = threadIdx.x >> 6;
    int lane = threadIdx.x & 63;
    int gw = blockIdx.x * 4 + wave;
    int m_base = gw * 16;
    if (m_base >= M) return;
    int l16 = lane & 15, quad = lane >> 4;

    const bf16x8* Arow = (const bf16x8*)(A + ((long)(m_base + l16) * D + quad * 8));
    bf16x8 afrag[8];
#pragma unroll
    for (int s = 0; s < 8; ++s) afrag[s] = Arow[s * 4];

#pragma unroll 2
    for (int nt = 0; nt < 16; ++nt) {
        int ncol = nt * 16 + l16;
        const bf16x8* Wrow = (const bf16x8*)(W + ((long)ncol * D + quad * 8));
        f32x4 acc[4];
#pragma unroll
        for (int c = 0; c < 4; ++c) acc[c] = (f32x4){0.f, 0.f, 0.f, 0.f};
#pragma unroll
        for (int c = 0; c < 4; ++c)
            acc[c] = __builtin_amdgcn_mfma_f32_16x16x32_bf16(afrag[c], Wrow[c * 4], acc[c], 0, 0, 0);
#pragma unroll
        for (int c = 0; c < 4; ++c)
            acc[c] = __builtin_amdgcn_mfma_f32_16x16x32_bf16(afrag[c + 4], Wrow[(c + 4) * 4], acc[c], 0, 0, 0);
        float b = bias[ncol];
#pragma unroll
        for (int r = 0; r < 4; ++r) {
            int row = m_base + quad * 4 + r;
            float t = acc[0][r] + acc[1][r] + acc[2][r] + acc[3][r] + b;
            G[(long)row * D + ncol] = f2bf(gelu_tanh(t));
        }
    }
}

// GEMM2: out = BN2(h + G @ W2^T + b2)
__global__ __launch_bounds__(256) void k_gemm2(
    const unsigned short* __restrict__ A, const unsigned short* __restrict__ W,
    const float* __restrict__ bias, const float* __restrict__ h,
    const float* __restrict__ s2, const float* __restrict__ sh2,
    float* __restrict__ out, int M)
{
    int wave = threadIdx.x >> 6;
    int lane = threadIdx.x & 63;
    int gw = blockIdx.x * 4 + wave;
    int m_base = gw * 16;
    if (m_base >= M) return;
    int l16 = lane & 15, quad = lane >> 4;

    const bf16x8* Arow = (const bf16x8*)(A + ((long)(m_base + l16) * D + quad * 8));
    bf16x8 afrag[8];
#pragma unroll
    for (int s = 0; s < 8; ++s) afrag[s] = Arow[s * 4];

#pragma unroll 2
    for (int nt = 0; nt < 16; ++nt) {
        int ncol = nt * 16 + l16;
        const bf16x8* Wrow = (const bf16x8*)(W + ((long)ncol * D + quad * 8));
        f32x4 acc[4];
#pragma unroll
        for (int c = 0; c < 4; ++c) acc[c] = (f32x4){0.f, 0.f, 0.f, 0.f};
#pragma unroll
        for (int c = 0; c < 4; ++c)
            acc[c] = __builtin_amdgcn_mfma_f32_16x16x32_bf16(afrag[c], Wrow[c * 4], acc[c], 0, 0, 0);
#pragma unroll
        for (int c = 0; c < 4; ++c)
            acc[c] = __builtin_amdgcn_mfma_f32_16x16x32_bf16(afrag[c + 4], Wrow[(c + 4) * 4], acc[c], 0, 0, 0);
        float b = bias[ncol];
        float sc = s2[ncol], sh = sh2[ncol];
#pragma unroll
        for (int r = 0; r < 4; ++r) {
            int row = m_base + quad * 4 + r;
            float f = acc[0][r] + acc[1][r] + acc[2][r] + acc[3][r] + b;
            float t = h[(long)row * D + ncol] + f;
            out[(long)row * D + ncol] = t * sc + sh;
        }
    }
}

extern "C" void kernel_launch(void* const* d_in, const int* in_sizes, int n_in,
                              void* d_out, int out_size, void* d_ws, size_t ws_size,
                              hipStream_t stream) {
    const float* x   = (const float*)d_in[0];
    const int*   ei  = (const int*)d_in[1];
    const float* ea  = (const float*)d_in[2];
    const float* W1  = (const float*)d_in[3];
    const float* b1  = (const float*)d_in[4];
    const float* W2  = (const float*)d_in[5];
    const float* b2  = (const float*)d_in[6];
    const float* g1  = (const float*)d_in[7];
    const float* be1 = (const float*)d_in[8];
    const float* m1  = (const float*)d_in[9];
    const float* v1  = (const float*)d_in[10];
    const float* g2  = (const float*)d_in[11];
    const float* be2 = (const float*)d_in[12];
    const float* m2  = (const float*)d_in[13];
    const float* v2  = (const float*)d_in[14];
    float* out = (float*)d_out;

    int N_ = in_sizes[0] / D;
    int E_ = in_sizes[2] / D;

    char* ws = (char*)d_ws;
    size_t off = 0;
    float* h = (float*)(ws + off);                      off += (size_t)N_ * D * 4;
    unsigned short* abf = (unsigned short*)(ws + off);  off += (size_t)N_ * D * 2;
    unsigned short* gbf = (unsigned short*)(ws + off);  off += (size_t)N_ * D * 2;
    unsigned short* W1b = (unsigned short*)(ws + off);  off += (size_t)D * D * 2;
    unsigned short* W2b = (unsigned short*)(ws + off);  off += (size_t)D * D * 2;
    float* s1  = (float*)(ws + off); off += D * 4;
    float* sh1 = (float*)(ws + off); off += D * 4;
    float* s2  = (float*)(ws + off); off += D * 4;
    float* sh2 = (float*)(ws + off); off += D * 4;

    // Sort scratch overlaid in the gbf region: all consumers (k_agg) finish
    // before k_gemm1 writes gbf, and 1.8 MB << 25.6 MB. Keeps ws footprint
    // identical to the known-good R1 layout.
    int* counts   = (int*)gbf;
    int* cursor   = counts + N_;
    int* offs     = cursor + N_;          // N_+1 entries
    int* partials = offs + N_ + 1;        // 256 entries
    int* sorted   = partials + 256;       // E_ entries

    int nblkN = (N_ + 255) / 256;
    int nblkE = (E_ + 255) / 256;

    k_prep<<<(D * D + 255) / 256, 256, 0, stream>>>(W1, W2, W1b, W2b,
        g1, be1, m1, v1, g2, be2, m2, v2, s1, sh1, s2, sh2);
    k_zero<<<nblkN, 256, 0, stream>>>(counts, cursor, N_);
    k_hist<<<nblkE, 256, 0, stream>>>(ei, counts, E_);
    k_scan1<<<nblkN, 256, 0, stream>>>(counts, offs, partials, N_);
    k_scan2<<<1, 256, 0, stream>>>(partials, nblkN);
    k_scan3<<<nblkN, 256, 0, stream>>>(offs, partials, N_, E_);
    k_bucket<<<nblkE, 256, 0, stream>>>(ei, offs, cursor, sorted, E_);
    k_agg<<<(N_ + 3) / 4, 256, 0, stream>>>((const float4*)x, (const float4*)ea,
        ei, offs, sorted, s1, sh1, (float4*)h, (ushort4*)abf, N_, E_);

    int nwaves = (N_ + 15) / 16;
    int gblocks = (nwaves + 3) / 4;
    k_gemm1<<<gblocks, 256, 0, stream>>>(abf, W1b, b1, gbf, N_);
    k_gemm2<<<gblocks, 256, 0, stream>>>(gbf, W2b, b2, h, s2, sh2, out, N_);
}

// Round 3
// 655.362 us; speedup vs baseline: 2.3602x; 1.0613x over previous
//
#include <hip/hip_runtime.h>
#include <hip/hip_bf16.h>
#include <math.h>

#define D 256
#define D4 64      // D / 4
#define GSTRIDE 264  // 256 + 8 pad: keeps rows 16B-aligned (528B), kills LDS bank conflicts

typedef __attribute__((ext_vector_type(8))) short bf16x8;
typedef __attribute__((ext_vector_type(4))) float f32x4;

__device__ inline unsigned short f2bf(float f) {
    union { float f; unsigned u; } v; v.f = f;
    unsigned r = v.u + 0x7fffu + ((v.u >> 16) & 1u);   // RNE
    return (unsigned short)(r >> 16);
}
__device__ inline float bf2f(unsigned short u) {
    union { unsigned u; float f; } v; v.u = ((unsigned)u) << 16; return v.f;
}
__device__ inline float gelu_tanh(float t) {
    float z = 0.7978845608028654f * (t + 0.044715f * t * t * t);
    float e = __expf(2.f * z);
    return 0.5f * t * (2.f - 2.f / (e + 1.f));
}

// W1,W2 -> bf16; fold BN params; zero sort counters
__global__ __launch_bounds__(256) void k_prep(
    const float* __restrict__ W1, const float* __restrict__ W2,
    unsigned short* __restrict__ W1b, unsigned short* __restrict__ W2b,
    const float* g1, const float* be1, const float* m1, const float* v1,
    const float* g2, const float* be2, const float* m2, const float* v2,
    float* s1, float* sh1, float* r1, float* s2, float* sh2,
    int* counts, int* cursor, int N_)
{
    int i = blockIdx.x * 256 + threadIdx.x;
    if (i < D * D) {
        W1b[i] = f2bf(W1[i]);
        W2b[i] = f2bf(W2[i]);
    }
    if (i < N_) { counts[i] = 0; cursor[i] = 0; }
    if (i < D) {
        float sc1 = g1[i] * rsqrtf(v1[i] + 1e-5f);
        s1[i] = sc1; sh1[i] = be1[i] - m1[i] * sc1; r1[i] = 1.f / sc1;
        float sc2 = g2[i] * rsqrtf(v2[i] + 1e-5f);
        s2[i] = sc2; sh2[i] = be2[i] - m2[i] * sc2;
    }
}

// ---- counting sort of edges by dst ----
__global__ __launch_bounds__(256) void k_hist(const int* __restrict__ ei, int* counts, int E_) {
    int e = blockIdx.x * 256 + threadIdx.x;
    if (e < E_) atomicAdd(&counts[ei[E_ + e]], 1);
}

__global__ __launch_bounds__(256) void k_scan1(const int* __restrict__ counts,
                                               int* offs, int* partials, int n) {
    __shared__ int tmp[256];
    int tid = threadIdx.x, i = blockIdx.x * 256 + tid;
    int v = (i < n) ? counts[i] : 0;
    tmp[tid] = v; __syncthreads();
    for (int d = 1; d < 256; d <<= 1) {
        int t = (tid >= d) ? tmp[tid - d] : 0;
        __syncthreads();
        tmp[tid] += t;
        __syncthreads();
    }
    if (i < n) offs[i] = tmp[tid] - v;          // exclusive
    if (tid == 255) partials[blockIdx.x] = tmp[255];
}

__global__ __launch_bounds__(256) void k_scan2(int* partials, int nb) {
    __shared__ int tmp[256];
    int tid = threadIdx.x;
    int v = (tid < nb) ? partials[tid] : 0;
    tmp[tid] = v; __syncthreads();
    for (int d = 1; d < 256; d <<= 1) {
        int t = (tid >= d) ? tmp[tid - d] : 0;
        __syncthreads();
        tmp[tid] += t;
        __syncthreads();
    }
    if (tid < nb) partials[tid] = tmp[tid] - v; // exclusive
}

__global__ __launch_bounds__(256) void k_scan3(int* offs, const int* __restrict__ partials,
                                               int n, int E_) {
    int i = blockIdx.x * 256 + threadIdx.x;
    if (i < n) offs[i] += partials[blockIdx.x];
    if (i == 0) offs[n] = E_;
}

// sorted[pos] = {src, edge_id} so k_agg needs one load, not a dependent chain
__global__ __launch_bounds__(256) void k_bucket(const int* __restrict__ ei,
                                                const int* __restrict__ offs,
                                                int* cursor, int2* sorted, int E_) {
    int e = blockIdx.x * 256 + threadIdx.x;
    if (e < E_) {
        int d = ei[E_ + e];
        int pos = offs[d] + atomicAdd(&cursor[d], 1);
        sorted[pos] = make_int2(ei[e], e);
    }
}

// ---- aggregation: one wave per dst row; fuses h=2x+agg and BN1->bf16; writes ONLY abf ----
__global__ __launch_bounds__(256) void k_agg(
    const float4* __restrict__ x, const float4* __restrict__ ea,
    const int* __restrict__ offs, const int2* __restrict__ sorted,
    const float* __restrict__ s1, const float* __restrict__ sh1,
    ushort4* __restrict__ abf, int N_)
{
    int wave = threadIdx.x >> 6, lane = threadIdx.x & 63;
    int row = blockIdx.x * 4 + wave;
    if (row >= N_) return;
    float4 xv = x[(long)row * D4 + lane];
    float ax = 2.f * xv.x, ay = 2.f * xv.y, az = 2.f * xv.z, aw = 2.f * xv.w;
    int b = offs[row], en = offs[row + 1];
    for (int i = b; i < en; ++i) {
        int2 se = sorted[i];
        float4 sv = x[(long)se.x * D4 + lane];
        float4 av = ea[(long)se.y * D4 + lane];
        ax += fmaxf(sv.x + av.x, 0.f);
        ay += fmaxf(sv.y + av.y, 0.f);
        az += fmaxf(sv.z + av.z, 0.f);
        aw += fmaxf(sv.w + av.w, 0.f);
    }
    float4 sc = ((const float4*)s1)[lane];
    float4 sh = ((const float4*)sh1)[lane];
    ushort4 o;
    o.x = f2bf(ax * sc.x + sh.x);
    o.y = f2bf(ay * sc.y + sh.y);
    o.z = f2bf(az * sc.z + sh.z);
    o.w = f2bf(aw * sc.w + sh.w);
    abf[(long)row * D4 + lane] = o;
}

// ---- fused FFN: GEMM1 -> GELU -> (wave-local LDS transpose) -> GEMM2 -> residual+BN2 ----
// Residual h is reconstructed from abf: h = (a - sh1) / s1  (adds only bf16 rounding of h).
__global__ __launch_bounds__(256) void k_ffn(
    const unsigned short* __restrict__ A,    // abf [M,256]
    const unsigned short* __restrict__ W1,   // [256,256] bf16, row = out col
    const unsigned short* __restrict__ W2,
    const float* __restrict__ b1, const float* __restrict__ b2,
    const float* __restrict__ r1, const float* __restrict__ sh1,
    const float* __restrict__ s2, const float* __restrict__ sh2,
    float* __restrict__ out, int M)
{
    __shared__ __align__(16) unsigned short Gs[4][16][GSTRIDE];
    int wave = threadIdx.x >> 6, lane = threadIdx.x & 63;
    int m_base = (blockIdx.x * 4 + wave) * 16;
    if (m_base >= M) return;          // no block-wide barriers below: LDS is wave-local
    int l16 = lane & 15, quad = lane >> 4;

    const bf16x8* Arow = (const bf16x8*)(A + ((long)(m_base + l16) * D + quad * 8));
    bf16x8 frag[8];
#pragma unroll
    for (int s = 0; s < 8; ++s) frag[s] = Arow[s * 4];

    // GEMM1 + GELU -> LDS (C-layout scatter writes: 2 lanes/dword = conflict-free)
#pragma unroll 2
    for (int nt = 0; nt < 16; ++nt) {
        int ncol = nt * 16 + l16;
        const bf16x8* Wrow = (const bf16x8*)(W1 + ((long)ncol * D + quad * 8));
        f32x4 acc0 = {0.f, 0.f, 0.f, 0.f};
        f32x4 acc1 = {0.f, 0.f, 0.f, 0.f};
#pragma unroll
        for (int s = 0; s < 8; s += 2) {
            acc0 = __builtin_amdgcn_mfma_f32_16x16x32_bf16(frag[s],     Wrow[s * 4],       acc0, 0, 0, 0);
            acc1 = __builtin_amdgcn_mfma_f32_16x16x32_bf16(frag[s + 1], Wrow[(s + 1) * 4], acc1, 0, 0, 0);
        }
        float b = b1[ncol];
#pragma unroll
        for (int r = 0; r < 4; ++r) {
            float t = acc0[r] + acc1[r] + b;
            Gs[wave][quad * 4 + r][ncol] = f2bf(gelu_tanh(t));
        }
    }

    // reload G as A-operand fragments (b128, 2-way max bank aliasing = free)
#pragma unroll
    for (int s = 0; s < 8; ++s)
        frag[s] = *(const bf16x8*)&Gs[wave][l16][quad * 8 + s * 32];

    // GEMM2 + residual + BN2
#pragma unroll 2
    for (int nt = 0; nt < 16; ++nt) {
        int ncol = nt * 16 + l16;
        const bf16x8* Wrow = (const bf16x8*)(W2 + ((long)ncol * D + quad * 8));
        f32x4 acc0 = {0.f, 0.f, 0.f, 0.f};
        f32x4 acc1 = {0.f, 0.f, 0.f, 0.f};
#pragma unroll
        for (int s = 0; s < 8; s += 2) {
            acc0 = __builtin_amdgcn_mfma_f32_16x16x32_bf16(frag[s],     Wrow[s * 4],       acc0, 0, 0, 0);
            acc1 = __builtin_amdgcn_mfma_f32_16x16x32_bf16(frag[s + 1], Wrow[(s + 1) * 4], acc1, 0, 0, 0);
        }
        float b = b2[ncol], rr = r1[ncol], sh = sh1[ncol];
        float c2 = s2[ncol], h2 = sh2[ncol];
#pragma unroll
        for (int r = 0; r < 4; ++r) {
            int row = m_base + quad * 4 + r;
            float f = acc0[r] + acc1[r] + b;
            float hv = (bf2f(A[(long)row * D + ncol]) - sh) * rr;
            out[(long)row * D + ncol] = (hv + f) * c2 + h2;
        }
    }
}

extern "C" void kernel_launch(void* const* d_in, const int* in_sizes, int n_in,
                              void* d_out, int out_size, void* d_ws, size_t ws_size,
                              hipStream_t stream) {
    const float* x   = (const float*)d_in[0];
    const int*   ei  = (const int*)d_in[1];
    const float* ea  = (const float*)d_in[2];
    const float* W1  = (const float*)d_in[3];
    const float* b1  = (const float*)d_in[4];
    const float* W2  = (const float*)d_in[5];
    const float* b2  = (const float*)d_in[6];
    const float* g1  = (const float*)d_in[7];
    const float* be1 = (const float*)d_in[8];
    const float* m1  = (const float*)d_in[9];
    const float* v1  = (const float*)d_in[10];
    const float* g2  = (const float*)d_in[11];
    const float* be2 = (const float*)d_in[12];
    const float* m2  = (const float*)d_in[13];
    const float* v2  = (const float*)d_in[14];
    float* out = (float*)d_out;

    int N_ = in_sizes[0] / D;
    int E_ = in_sizes[2] / D;

    char* ws = (char*)d_ws;
    size_t off = 0;
    unsigned short* abf = (unsigned short*)(ws + off);  off += (size_t)N_ * D * 2;
    unsigned short* W1b = (unsigned short*)(ws + off);  off += (size_t)D * D * 2;
    unsigned short* W2b = (unsigned short*)(ws + off);  off += (size_t)D * D * 2;
    float* s1  = (float*)(ws + off); off += D * 4;
    float* sh1 = (float*)(ws + off); off += D * 4;
    float* r1  = (float*)(ws + off); off += D * 4;
    float* s2  = (float*)(ws + off); off += D * 4;
    float* sh2 = (float*)(ws + off); off += D * 4;
    int* counts   = (int*)(ws + off); off += (size_t)N_ * 4;
    int* cursor   = (int*)(ws + off); off += (size_t)N_ * 4;
    int* offs     = (int*)(ws + off); off += (size_t)(N_ + 1) * 4;
    int* partials = (int*)(ws + off); off += 256 * 4;
    int2* sorted  = (int2*)(ws + off); off += (size_t)E_ * 8;

    int nblkN = (N_ + 255) / 256;
    int nblkE = (E_ + 255) / 256;

    k_prep<<<(D * D + 255) / 256, 256, 0, stream>>>(W1, W2, W1b, W2b,
        g1, be1, m1, v1, g2, be2, m2, v2, s1, sh1, r1, s2, sh2, counts, cursor, N_);
    k_hist<<<nblkE, 256, 0, stream>>>(ei, counts, E_);
    k_scan1<<<nblkN, 256, 0, stream>>>(counts, offs, partials, N_);
    k_scan2<<<1, 256, 0, stream>>>(partials, nblkN);
    k_scan3<<<nblkN, 256, 0, stream>>>(offs, partials, N_, E_);
    k_bucket<<<nblkE, 256, 0, stream>>>(ei, offs, cursor, sorted, E_);
    k_agg<<<(N_ + 3) / 4, 256, 0, stream>>>((const float4*)x, (const float4*)ea,
        offs, sorted, s1, sh1, (ushort4*)abf, N_);

    int mtiles = (N_ + 15) / 16;
    k_ffn<<<(mtiles + 3) / 4, 256, 0, stream>>>(abf, W1b, W2b, b1, b2,
        r1, sh1, s2, sh2, out, N_);
}

// Round 4
// 652.290 us; speedup vs baseline: 2.3713x; 1.0047x over previous
//
#include <hip/hip_runtime.h>
#include <hip/hip_bf16.h>
#include <math.h>

#define D 256
#define D4 64       // D / 4
#define GS 264      // bf16 LDS row stride: 16B-aligned rows (528B), canonical bank spread

typedef __attribute__((ext_vector_type(8))) short bf16x8;
typedef __attribute__((ext_vector_type(4))) float f32x4;

__device__ inline unsigned short f2bf(float f) {
    union { float f; unsigned u; } v; v.f = f;
    unsigned r = v.u + 0x7fffu + ((v.u >> 16) & 1u);   // RNE
    return (unsigned short)(r >> 16);
}
__device__ inline float bf2f(unsigned short u) {
    union { unsigned u; float f; } v; v.u = ((unsigned)u) << 16; return v.f;
}
__device__ inline float gelu_tanh(float t) {
    float z = 0.7978845608028654f * (t + 0.044715f * t * t * t);
    float e = __expf(2.f * z);
    return 0.5f * t * (2.f - 2.f / (e + 1.f));
}

// W1,W2 -> bf16; fold BN params; zero histogram counters
__global__ __launch_bounds__(256) void k_prep(
    const float* __restrict__ W1, const float* __restrict__ W2,
    unsigned short* __restrict__ W1b, unsigned short* __restrict__ W2b,
    const float* g1, const float* be1, const float* m1, const float* v1,
    const float* g2, const float* be2, const float* m2, const float* v2,
    float* s1, float* sh1, float* r1, float* s2, float* sh2,
    int* counts, int N_)
{
    int i = blockIdx.x * 256 + threadIdx.x;
    if (i < D * D) {
        W1b[i] = f2bf(W1[i]);
        W2b[i] = f2bf(W2[i]);
    }
    if (i < N_) counts[i] = 0;
    if (i < D) {
        float sc1 = g1[i] * rsqrtf(v1[i] + 1e-5f);
        s1[i] = sc1; sh1[i] = be1[i] - m1[i] * sc1; r1[i] = 1.f / sc1;
        float sc2 = g2[i] * rsqrtf(v2[i] + 1e-5f);
        s2[i] = sc2; sh2[i] = be2[i] - m2[i] * sc2;
    }
}

// ---- counting sort of edges by dst ----
__global__ __launch_bounds__(256) void k_hist(const int* __restrict__ ei, int* counts, int E_) {
    int e = blockIdx.x * 256 + threadIdx.x;
    if (e < E_) atomicAdd(&counts[ei[E_ + e]], 1);
}

__global__ __launch_bounds__(256) void k_scan1(const int* __restrict__ counts,
                                               int* offs, int* partials, int n) {
    __shared__ int tmp[256];
    int tid = threadIdx.x, i = blockIdx.x * 256 + tid;
    int v = (i < n) ? counts[i] : 0;
    tmp[tid] = v; __syncthreads();
    for (int d = 1; d < 256; d <<= 1) {
        int t = (tid >= d) ? tmp[tid - d] : 0;
        __syncthreads();
        tmp[tid] += t;
        __syncthreads();
    }
    if (i < n) offs[i] = tmp[tid] - v;          // exclusive
    if (tid == 255) partials[blockIdx.x] = tmp[255];
}

__global__ __launch_bounds__(256) void k_scan2(int* partials, int nb) {
    __shared__ int tmp[256];
    int tid = threadIdx.x;
    int v = (tid < nb) ? partials[tid] : 0;
    tmp[tid] = v; __syncthreads();
    for (int d = 1; d < 256; d <<= 1) {
        int t = (tid >= d) ? tmp[tid - d] : 0;
        __syncthreads();
        tmp[tid] += t;
        __syncthreads();
    }
    if (tid < nb) partials[tid] = tmp[tid] - v; // exclusive
}

// adds block prefix; also seeds cursor = offs so k_bucket needs one fewer load
__global__ __launch_bounds__(256) void k_scan3(int* offs, int* cursor,
                                               const int* __restrict__ partials,
                                               int n, int E_) {
    int i = blockIdx.x * 256 + threadIdx.x;
    if (i < n) {
        int v = offs[i] + partials[blockIdx.x];
        offs[i] = v;
        cursor[i] = v;
    }
    if (i == 0) offs[n] = E_;
}

// sorted[pos] = {src, edge_id}
__global__ __launch_bounds__(256) void k_bucket(const int* __restrict__ ei,
                                                int* cursor, int2* sorted, int E_) {
    int e = blockIdx.x * 256 + threadIdx.x;
    if (e < E_) {
        int d = ei[E_ + e];
        int pos = atomicAdd(&cursor[d], 1);
        sorted[pos] = make_int2(ei[e], e);
    }
}

// ---- fully fused: aggregation (gather, no atomics) + BN1 -> LDS bf16 tile
//      -> GEMM1 -> GELU -> LDS -> GEMM2 -> residual + BN2 -> out
// Block = 4 waves = one 16-row tile. LDS 16.9 KB -> 8 blocks/CU.
__global__ __launch_bounds__(256) void k_fused(
    const float4* __restrict__ x, const float4* __restrict__ ea,
    const int* __restrict__ offs, const int2* __restrict__ sorted,
    const float* __restrict__ s1, const float* __restrict__ sh1,
    const float* __restrict__ r1,
    const unsigned short* __restrict__ W1, const unsigned short* __restrict__ W2,
    const float* __restrict__ b1, const float* __restrict__ b2,
    const float* __restrict__ s2, const float* __restrict__ sh2,
    float* __restrict__ out, int M)
{
    __shared__ __align__(16) unsigned short As[16][GS];  // bf16(BN1(h)) tile
    __shared__ __align__(16) unsigned short Gsm[16][GS]; // bf16(gelu) tile

    int wave = threadIdx.x >> 6, lane = threadIdx.x & 63;
    int m_base = blockIdx.x * 16;

    // ---- phase 1: aggregate 4 rows per wave ----
    float4 sc1v = ((const float4*)s1)[lane];
    float4 sh1v = ((const float4*)sh1)[lane];
#pragma unroll
    for (int rr = 0; rr < 4; ++rr) {
        int tr = wave * 4 + rr;
        int row = m_base + tr;
        if (row < M) {
            float4 xv = x[(long)row * D4 + lane];
            float ax = 2.f * xv.x, ay = 2.f * xv.y, az = 2.f * xv.z, aw = 2.f * xv.w;
            int b = offs[row], en = offs[row + 1];
            for (int i = b; i < en; ++i) {
                int2 se = sorted[i];
                float4 sv = x[(long)se.x * D4 + lane];
                float4 av = ea[(long)se.y * D4 + lane];
                ax += fmaxf(sv.x + av.x, 0.f);
                ay += fmaxf(sv.y + av.y, 0.f);
                az += fmaxf(sv.z + av.z, 0.f);
                aw += fmaxf(sv.w + av.w, 0.f);
            }
            ushort4 o;
            o.x = f2bf(ax * sc1v.x + sh1v.x);
            o.y = f2bf(ay * sc1v.y + sh1v.y);
            o.z = f2bf(az * sc1v.z + sh1v.z);
            o.w = f2bf(aw * sc1v.w + sh1v.w);
            *(ushort4*)&As[tr][lane * 4] = o;
        }
    }
    __syncthreads();

    int l16 = lane & 15, quad = lane >> 4;

    // A-frags from LDS (A[m=l16][k=quad*8 + s*32 + j])
    bf16x8 frag[8];
#pragma unroll
    for (int s = 0; s < 8; ++s)
        frag[s] = *(const bf16x8*)&As[l16][quad * 8 + s * 32];

    // ---- phase 2: GEMM1 + GELU -> Gsm; wave handles n-tiles wave*4..wave*4+3 ----
#pragma unroll
    for (int t = 0; t < 4; ++t) {
        int ncol = (wave * 4 + t) * 16 + l16;
        const bf16x8* Wrow = (const bf16x8*)(W1 + ((long)ncol * D + quad * 8));
        f32x4 acc0 = {0.f, 0.f, 0.f, 0.f};
        f32x4 acc1 = {0.f, 0.f, 0.f, 0.f};
#pragma unroll
        for (int s = 0; s < 8; s += 2) {
            acc0 = __builtin_amdgcn_mfma_f32_16x16x32_bf16(frag[s],     Wrow[s * 4],       acc0, 0, 0, 0);
            acc1 = __builtin_amdgcn_mfma_f32_16x16x32_bf16(frag[s + 1], Wrow[(s + 1) * 4], acc1, 0, 0, 0);
        }
        float b = b1[ncol];
#pragma unroll
        for (int r = 0; r < 4; ++r) {
            float v = acc0[r] + acc1[r] + b;
            Gsm[quad * 4 + r][ncol] = f2bf(gelu_tanh(v));
        }
    }
    __syncthreads();

#pragma unroll
    for (int s = 0; s < 8; ++s)
        frag[s] = *(const bf16x8*)&Gsm[l16][quad * 8 + s * 32];

    // ---- phase 3: GEMM2 + residual + BN2 ----
#pragma unroll
    for (int t = 0; t < 4; ++t) {
        int ncol = (wave * 4 + t) * 16 + l16;
        const bf16x8* Wrow = (const bf16x8*)(W2 + ((long)ncol * D + quad * 8));
        f32x4 acc0 = {0.f, 0.f, 0.f, 0.f};
        f32x4 acc1 = {0.f, 0.f, 0.f, 0.f};
#pragma unroll
        for (int s = 0; s < 8; s += 2) {
            acc0 = __builtin_amdgcn_mfma_f32_16x16x32_bf16(frag[s],     Wrow[s * 4],       acc0, 0, 0, 0);
            acc1 = __builtin_amdgcn_mfma_f32_16x16x32_bf16(frag[s + 1], Wrow[(s + 1) * 4], acc1, 0, 0, 0);
        }
        float b = b2[ncol], rr1 = r1[ncol], sh = sh1[ncol];
        float c2 = s2[ncol], h2 = sh2[ncol];
#pragma unroll
        for (int r = 0; r < 4; ++r) {
            int tr = quad * 4 + r;
            int row = m_base + tr;
            if (row < M) {
                float f = acc0[r] + acc1[r] + b;
                float hv = (bf2f(As[tr][ncol]) - sh) * rr1;   // h from LDS bf16 tile
                out[(long)row * D + ncol] = (hv + f) * c2 + h2;
            }
        }
    }
}

extern "C" void kernel_launch(void* const* d_in, const int* in_sizes, int n_in,
                              void* d_out, int out_size, void* d_ws, size_t ws_size,
                              hipStream_t stream) {
    const float* x   = (const float*)d_in[0];
    const int*   ei  = (const int*)d_in[1];
    const float* ea  = (const float*)d_in[2];
    const float* W1  = (const float*)d_in[3];
    const float* b1  = (const float*)d_in[4];
    const float* W2  = (const float*)d_in[5];
    const float* b2  = (const float*)d_in[6];
    const float* g1  = (const float*)d_in[7];
    const float* be1 = (const float*)d_in[8];
    const float* m1  = (const float*)d_in[9];
    const float* v1  = (const float*)d_in[10];
    const float* g2  = (const float*)d_in[11];
    const float* be2 = (const float*)d_in[12];
    const float* m2  = (const float*)d_in[13];
    const float* v2  = (const float*)d_in[14];
    float* out = (float*)d_out;

    int N_ = in_sizes[0] / D;
    int E_ = in_sizes[2] / D;

    char* ws = (char*)d_ws;
    size_t off = 0;
    unsigned short* W1b = (unsigned short*)(ws + off);  off += (size_t)D * D * 2;
    unsigned short* W2b = (unsigned short*)(ws + off);  off += (size_t)D * D * 2;
    float* s1  = (float*)(ws + off); off += D * 4;
    float* sh1 = (float*)(ws + off); off += D * 4;
    float* r1  = (float*)(ws + off); off += D * 4;
    float* s2  = (float*)(ws + off); off += D * 4;
    float* sh2 = (float*)(ws + off); off += D * 4;
    int* counts   = (int*)(ws + off); off += (size_t)N_ * 4;
    int* cursor   = (int*)(ws + off); off += (size_t)N_ * 4;
    int* offs     = (int*)(ws + off); off += (size_t)(N_ + 1) * 4;
    int* partials = (int*)(ws + off); off += 256 * 4;
    int2* sorted  = (int2*)(ws + off); off += (size_t)E_ * 8;

    int nblkN = (N_ + 255) / 256;
    int nblkE = (E_ + 255) / 256;

    k_prep<<<(D * D + 255) / 256, 256, 0, stream>>>(W1, W2, W1b, W2b,
        g1, be1, m1, v1, g2, be2, m2, v2, s1, sh1, r1, s2, sh2, counts, N_);
    k_hist<<<nblkE, 256, 0, stream>>>(ei, counts, E_);
    k_scan1<<<nblkN, 256, 0, stream>>>(counts, offs, partials, N_);
    k_scan2<<<1, 256, 0, stream>>>(partials, nblkN);
    k_scan3<<<nblkN, 256, 0, stream>>>(offs, cursor, partials, N_, E_);
    k_bucket<<<nblkE, 256, 0, stream>>>(ei, cursor, sorted, E_);

    int mtiles = (N_ + 15) / 16;
    k_fused<<<mtiles, 256, 0, stream>>>((const float4*)x, (const float4*)ea,
        offs, sorted, s1, sh1, r1, W1b, W2b, b1, b2, s2, sh2, out, N_);
}